// Round 7
// baseline (815.876 us; speedup 1.0000x reference)
//
#include <hip/hip_runtime.h>

#define BB   4
#define CC   256
#define NPIX 4096
#define AST2 40    // mfma-core LDS row stride (shorts), 80 B, 16B-aligned
#define YST  72    // ygemm LDS row stride (shorts), 144 B, 16B-aligned

typedef __attribute__((ext_vector_type(8)))  short bf16x8;
typedef __attribute__((ext_vector_type(4)))  short short4v;
typedef __attribute__((ext_vector_type(16))) float f32x16;

__device__ __forceinline__ short f2bf(float f) {
    unsigned u = __float_as_uint(f);
    u = u + 0x7fff + ((u >> 16) & 1);   // RNE
    return (short)(u >> 16);
}
__device__ __forceinline__ float bf2f(short s) {
    return __uint_as_float(((unsigned)(unsigned short)s) << 16);
}
__device__ __forceinline__ void split_bf(float v, short& hi, short& lo) {
    hi = f2bf(v);
    lo = f2bf(v - bf2f(hi));
}
__device__ __forceinline__ int cdrow(int r, int l5) {
    return (r & 3) + 8 * (r >> 2) + 4 * l5;   // verified m74/m101 C/D row map
}

// ---------------------------------------------------------------------------
// hi/lo split-bf16 MFMA core: 128x128 tile, K=256, register-prefetch pipelined.
// ---------------------------------------------------------------------------
__device__ __forceinline__ void mfma_core_hilo(
    const short* __restrict__ Ahi, const short* __restrict__ Alo,
    const short* __restrict__ Bhi, const short* __restrict__ Blo,
    f32x16 acc[2][2])
{
    __shared__ short LAh[128 * AST2], LAl[128 * AST2];
    __shared__ short LBh[128 * AST2], LBl[128 * AST2];
    const int t = threadIdx.x;
    const int lane = t & 63, w = t >> 6;
    const int l31 = lane & 31, l5 = lane >> 5;
    const int nq = (w & 1) * 64, mq = (w >> 1) * 64;
    const int sr = t >> 1;
    const int sk = (t & 1) * 16;
    const size_t gs = (size_t)sr * 256 + sk;
    const int ls = sr * AST2 + sk;

    // prologue: prefetch k0 = 0
    bf16x8 rAh0 = *(const bf16x8*)(Ahi + gs);
    bf16x8 rAh1 = *(const bf16x8*)(Ahi + gs + 8);
    bf16x8 rAl0 = *(const bf16x8*)(Alo + gs);
    bf16x8 rAl1 = *(const bf16x8*)(Alo + gs + 8);
    bf16x8 rBh0 = *(const bf16x8*)(Bhi + gs);
    bf16x8 rBh1 = *(const bf16x8*)(Bhi + gs + 8);
    bf16x8 rBl0 = *(const bf16x8*)(Blo + gs);
    bf16x8 rBl1 = *(const bf16x8*)(Blo + gs + 8);

    for (int k0 = 0; k0 < 256; k0 += 32) {
        __syncthreads();
        *(bf16x8*)&LAh[ls]     = rAh0;
        *(bf16x8*)&LAh[ls + 8] = rAh1;
        *(bf16x8*)&LAl[ls]     = rAl0;
        *(bf16x8*)&LAl[ls + 8] = rAl1;
        *(bf16x8*)&LBh[ls]     = rBh0;
        *(bf16x8*)&LBh[ls + 8] = rBh1;
        *(bf16x8*)&LBl[ls]     = rBl0;
        *(bf16x8*)&LBl[ls + 8] = rBl1;
        __syncthreads();
        if (k0 + 32 < 256) {   // issue next step's loads; they land during MFMA phase
            size_t g = gs + k0 + 32;
            rAh0 = *(const bf16x8*)(Ahi + g);
            rAh1 = *(const bf16x8*)(Ahi + g + 8);
            rAl0 = *(const bf16x8*)(Alo + g);
            rAl1 = *(const bf16x8*)(Alo + g + 8);
            rBh0 = *(const bf16x8*)(Bhi + g);
            rBh1 = *(const bf16x8*)(Bhi + g + 8);
            rBl0 = *(const bf16x8*)(Blo + g);
            rBl1 = *(const bf16x8*)(Blo + g + 8);
        }
#pragma unroll
        for (int ks = 0; ks < 2; ks++) {
            bf16x8 ah[2], al[2], bh[2], bl[2];
#pragma unroll
            for (int s = 0; s < 2; s++) {
                int ra = (nq + s * 32 + l31) * AST2 + ks * 16 + l5 * 8;
                int rb = (mq + s * 32 + l31) * AST2 + ks * 16 + l5 * 8;
                ah[s] = *(const bf16x8*)&LAh[ra];
                al[s] = *(const bf16x8*)&LAl[ra];
                bh[s] = *(const bf16x8*)&LBh[rb];
                bl[s] = *(const bf16x8*)&LBl[rb];
            }
#pragma unroll
            for (int s = 0; s < 2; s++)
#pragma unroll
                for (int u = 0; u < 2; u++) {
                    acc[s][u] = __builtin_amdgcn_mfma_f32_32x32x16_bf16(ah[s], bh[u], acc[s][u], 0, 0, 0);
                    acc[s][u] = __builtin_amdgcn_mfma_f32_32x32x16_bf16(ah[s], bl[u], acc[s][u], 0, 0, 0);
                    acc[s][u] = __builtin_amdgcn_mfma_f32_32x32x16_bf16(al[s], bh[u], acc[s][u], 0, 0, 0);
                }
        }
    }
}

// Single-bf16 variant (output GEMM), pipelined.
__device__ __forceinline__ void mfma_core_single(
    const short* __restrict__ A, const short* __restrict__ B, f32x16 acc[2][2])
{
    __shared__ short LA[128 * AST2], LB[128 * AST2];
    const int t = threadIdx.x;
    const int lane = t & 63, w = t >> 6;
    const int l31 = lane & 31, l5 = lane >> 5;
    const int nq = (w & 1) * 64, mq = (w >> 1) * 64;
    const int sr = t >> 1;
    const int sk = (t & 1) * 16;
    const size_t gs = (size_t)sr * 256 + sk;
    const int ls = sr * AST2 + sk;

    bf16x8 rA0 = *(const bf16x8*)(A + gs);
    bf16x8 rA1 = *(const bf16x8*)(A + gs + 8);
    bf16x8 rB0 = *(const bf16x8*)(B + gs);
    bf16x8 rB1 = *(const bf16x8*)(B + gs + 8);

    for (int k0 = 0; k0 < 256; k0 += 32) {
        __syncthreads();
        *(bf16x8*)&LA[ls]     = rA0;
        *(bf16x8*)&LA[ls + 8] = rA1;
        *(bf16x8*)&LB[ls]     = rB0;
        *(bf16x8*)&LB[ls + 8] = rB1;
        __syncthreads();
        if (k0 + 32 < 256) {
            size_t g = gs + k0 + 32;
            rA0 = *(const bf16x8*)(A + g);
            rA1 = *(const bf16x8*)(A + g + 8);
            rB0 = *(const bf16x8*)(B + g);
            rB1 = *(const bf16x8*)(B + g + 8);
        }
#pragma unroll
        for (int ks = 0; ks < 2; ks++) {
            bf16x8 a[2], b[2];
#pragma unroll
            for (int s = 0; s < 2; s++) {
                a[s] = *(const bf16x8*)&LA[(nq + s * 32 + l31) * AST2 + ks * 16 + l5 * 8];
                b[s] = *(const bf16x8*)&LB[(mq + s * 32 + l31) * AST2 + ks * 16 + l5 * 8];
            }
#pragma unroll
            for (int s = 0; s < 2; s++)
#pragma unroll
                for (int u = 0; u < 2; u++)
                    acc[s][u] = __builtin_amdgcn_mfma_f32_32x32x16_bf16(a[s], b[u], acc[s][u], 0, 0, 0);
        }
    }
}

// ---------------- pack kernels ----------------

__global__ __launch_bounds__(256) void pack_w_hilo(
    const float* __restrict__ w0, const float* __restrict__ w1, const float* __restrict__ w2,
    short* __restrict__ whi, short* __restrict__ wlo)
{
    int which = blockIdx.y;
    const float* w = which == 0 ? w0 : which == 1 ? w1 : w2;
    int idx = blockIdx.x * 1024 + threadIdx.x * 4;
    float4 v = *(const float4*)(w + idx);
    short4v h, l;
    short th, tl;
    split_bf(v.x, th, tl); h.x = th; l.x = tl;
    split_bf(v.y, th, tl); h.y = th; l.y = tl;
    split_bf(v.z, th, tl); h.z = th; l.z = tl;
    split_bf(v.w, th, tl); h.w = th; l.w = tl;
    *(short4v*)(whi + which * 65536 + idx) = h;
    *(short4v*)(wlo + which * 65536 + idx) = l;
}

__global__ __launch_bounds__(256) void pack_w_out(
    const float* __restrict__ w1, const float* __restrict__ w2, short* __restrict__ wob)
{
    int which = blockIdx.y;
    const float* w = which == 0 ? w1 : w2;
    int idx = blockIdx.x * 1024 + threadIdx.x * 4;
    float4 v = *(const float4*)(w + idx);
    short4v h;
    h.x = f2bf(v.x); h.y = f2bf(v.y); h.z = f2bf(v.z); h.w = f2bf(v.w);
    *(short4v*)(wob + which * 65536 + idx) = h;
}

// transpose + split: [b][256][4096] fp32 -> [b][4096][256] hi/lo bf16. grid (128,8,4)
__global__ __launch_bounds__(256) void pack_t_split(
    const float* __restrict__ in, short* __restrict__ ohi, short* __restrict__ olo)
{
    __shared__ short Th[32][36], Tl[32][36];
    const int b  = blockIdx.z;
    const int n0 = blockIdx.x * 32;
    const int c0 = blockIdx.y * 32;
    const float* src = in + (size_t)b * CC * NPIX;
    const int t = threadIdx.x;
    const int r = t >> 3, q = t & 7;
    float4 v = *(const float4*)(src + (size_t)(c0 + r) * NPIX + n0 + q * 4);
    short h, l;
    split_bf(v.x, h, l); Th[q * 4 + 0][r] = h; Tl[q * 4 + 0][r] = l;
    split_bf(v.y, h, l); Th[q * 4 + 1][r] = h; Tl[q * 4 + 1][r] = l;
    split_bf(v.z, h, l); Th[q * 4 + 2][r] = h; Tl[q * 4 + 2][r] = l;
    split_bf(v.w, h, l); Th[q * 4 + 3][r] = h; Tl[q * 4 + 3][r] = l;
    __syncthreads();
    short4v oh, ol;
    oh.x = Th[r][q * 4 + 0]; ol.x = Tl[r][q * 4 + 0];
    oh.y = Th[r][q * 4 + 1]; ol.y = Tl[r][q * 4 + 1];
    oh.z = Th[r][q * 4 + 2]; ol.z = Tl[r][q * 4 + 2];
    oh.w = Th[r][q * 4 + 3]; ol.w = Tl[r][q * 4 + 3];
    size_t o = (size_t)b * CC * NPIX + (size_t)(n0 + r) * 256 + c0 + q * 4;
    *(short4v*)(ohi + o) = oh;
    *(short4v*)(olo + o) = ol;
}

// Vt[c][m] = x3b.flat[m*256+c] (already bf16). grid (128,8,4)
__global__ __launch_bounds__(256) void packVt_bf(
    const short* __restrict__ x3b, short* __restrict__ Vt)
{
    __shared__ short T[32][33];
    const int b  = blockIdx.z;
    const int m0 = blockIdx.x * 32;
    const int c0 = blockIdx.y * 32;
    const short* in = x3b + (size_t)b * CC * NPIX;
    short* out = Vt + (size_t)b * CC * NPIX;
    const int t = threadIdx.x;
    const int r = t >> 3, q = t & 7;
    short4v v = *(const short4v*)(in + (size_t)(m0 + r) * CC + c0 + q * 4);
    T[q * 4 + 0][r] = v.x;
    T[q * 4 + 1][r] = v.y;
    T[q * 4 + 2][r] = v.z;
    T[q * 4 + 3][r] = v.w;
    __syncthreads();
    short4v o;
    o.x = T[r][q * 4 + 0];
    o.y = T[r][q * 4 + 1];
    o.z = T[r][q * 4 + 2];
    o.w = T[r][q * 4 + 3];
    *(short4v*)(out + (size_t)(c0 + r) * NPIX + m0 + q * 4) = o;
}

// ---------------- GEMM kernels ----------------

// proj. grid (32, 2, 12). p=0 -> x1 hi/lo, p=1 -> x2 fp32, p=2 -> x3 bf16.
__global__ __launch_bounds__(256) void proj_mfma(
    const short* __restrict__ wphi, const short* __restrict__ wplo,
    const short* __restrict__ xthi, const short* __restrict__ xtlo,
    const float* __restrict__ b_teta, const float* __restrict__ b_fi,
    const float* __restrict__ b_gi,
    short* __restrict__ x1hi, short* __restrict__ x1lo,
    float* __restrict__ x2, short* __restrict__ x3b)
{
    const int z = blockIdx.z, p = z >> 2, b = z & 3;
    const int n0 = blockIdx.x * 128, c0 = blockIdx.y * 128;
    const size_t CN = (size_t)CC * NPIX;
    const short* Ah = wphi + p * 65536 + c0 * 256;
    const short* Al = wplo + p * 65536 + c0 * 256;
    const short* Bh = xthi + (size_t)b * CN + (size_t)n0 * 256;
    const short* Bl = xtlo + (size_t)b * CN + (size_t)n0 * 256;
    const float* bias = p == 0 ? b_teta : p == 1 ? b_fi : b_gi;

    f32x16 acc[2][2] = {};
    mfma_core_hilo(Ah, Al, Bh, Bl, acc);

    const int t = threadIdx.x, lane = t & 63, w = t >> 6;
    const int l31 = lane & 31, l5 = lane >> 5;
    const int aq = (w & 1) * 64, bq = (w >> 1) * 64;
#pragma unroll
    for (int s = 0; s < 2; s++)
#pragma unroll
        for (int u = 0; u < 2; u++)
#pragma unroll
            for (int r = 0; r < 16; r++) {
                int c = c0 + aq + s * 32 + cdrow(r, l5);
                int n = n0 + bq + u * 32 + l31;
                float v = acc[s][u][r] + bias[c];
                size_t o = (size_t)b * CN + (size_t)c * NPIX + n;
                if (p == 0) {
                    short h, l; split_bf(v, h, l);
                    x1hi[o] = h; x1lo[o] = l;
                } else if (p == 1) {
                    x2[o] = v;
                } else {
                    x3b[o] = f2bf(v);
                }
            }
}

// scores. grid (32, 32) per batch
__global__ __launch_bounds__(256) void scores_mfma(
    const short* __restrict__ x1hi, const short* __restrict__ x1lo,
    const short* __restrict__ x2thi, const short* __restrict__ x2tlo,
    float* __restrict__ S)
{
    const int m0 = blockIdx.x * 128, n0 = blockIdx.y * 128;
    f32x16 acc[2][2] = {};
    mfma_core_hilo(x1hi + (size_t)n0 * 256, x1lo + (size_t)n0 * 256,
                   x2thi + (size_t)m0 * 256, x2tlo + (size_t)m0 * 256, acc);

    const int t = threadIdx.x, lane = t & 63, w = t >> 6;
    const int l31 = lane & 31, l5 = lane >> 5;
    const int aq = (w & 1) * 64, bq = (w >> 1) * 64;
#pragma unroll
    for (int s = 0; s < 2; s++)
#pragma unroll
        for (int u = 0; u < 2; u++)
#pragma unroll
            for (int r = 0; r < 16; r++) {
                int n = n0 + aq + s * 32 + cdrow(r, l5);
                int m = m0 + bq + u * 32 + l31;
                S[(size_t)n * NPIX + m] = acc[s][u][r];
            }
}

// out: relu(x + bias + W.Y^T), single batch. grid (32, 4)
__global__ __launch_bounds__(256) void out_mfma(
    const short* __restrict__ wob,
    const float* __restrict__ b_o1, const float* __restrict__ b_o2,
    const short* __restrict__ Y1s, const short* __restrict__ Y2s,
    const float* __restrict__ x, float* __restrict__ out, int b)
{
    const int ch0 = blockIdx.y * 128;
    const int pix0 = blockIdx.x * 128;
    const short* W = wob + (ch0 < 256 ? 0 : 65536) + (size_t)(ch0 & 255) * 256;
    const short* Y = (ch0 < 256 ? Y1s : Y2s) + (size_t)pix0 * 256;
    const float* bias = ch0 < 256 ? b_o1 : b_o2;

    f32x16 acc[2][2] = {};
    mfma_core_single(W, Y, acc);

    const int t = threadIdx.x, lane = t & 63, w = t >> 6;
    const int l31 = lane & 31, l5 = lane >> 5;
    const int aq = (w & 1) * 64, bq = (w >> 1) * 64;
#pragma unroll
    for (int s = 0; s < 2; s++)
#pragma unroll
        for (int u = 0; u < 2; u++)
#pragma unroll
            for (int r = 0; r < 16; r++) {
                int ch = ch0 + aq + s * 32 + cdrow(r, l5);
                int pix = pix0 + bq + u * 32 + l31;
                int chm = ch & 255;
                float v = acc[s][u][r] + bias[chm] +
                          x[((size_t)b * CC + chm) * NPIX + pix];
                out[((size_t)b * 2 * CC + ch) * NPIX + pix] = fmaxf(v, 0.0f);
            }
}

// ---------------- fused softmax stats ----------------
// One S sweep: complete row stats per 32-row stripe + col partials.
// grid (128), 256 threads; thread t owns cols {t + k*256}.
__global__ __launch_bounds__(256) void stats_fused(
    const float* __restrict__ S,
    float* __restrict__ rowm, float* __restrict__ rowli,
    float* __restrict__ pcm, float* __restrict__ pcl)
{
    const int r0 = blockIdx.x * 32;
    const int t = threadIdx.x;
    const int w = t >> 6, lane = t & 63;
    __shared__ float rpart[32][4];
    __shared__ float rowMsh[32];

    float cmx[16];
#pragma unroll
    for (int k = 0; k < 16; k++) cmx[k] = -1e30f;

    // phase A: maxes
    for (int r = 0; r < 32; r++) {
        const float* sp = S + (size_t)(r0 + r) * NPIX + t;
        float rmx = -1e30f;
#pragma unroll
        for (int k = 0; k < 16; k++) {
            float v = sp[k * 256];
            cmx[k] = fmaxf(cmx[k], v);
            rmx = fmaxf(rmx, v);
        }
        for (int off = 32; off; off >>= 1) rmx = fmaxf(rmx, __shfl_xor(rmx, off, 64));
        if (lane == 0) rpart[r][w] = rmx;
    }
    __syncthreads();
    if (t < 32) {
        float m = fmaxf(fmaxf(rpart[t][0], rpart[t][1]), fmaxf(rpart[t][2], rpart[t][3]));
        rowMsh[t] = m;
        rowm[r0 + t] = m;
    }
    __syncthreads();

    // phase B: sums (stripe is L2-resident on re-read)
    float csum[16];
#pragma unroll
    for (int k = 0; k < 16; k++) csum[k] = 0.0f;
    for (int r = 0; r < 32; r++) {
        const float* sp = S + (size_t)(r0 + r) * NPIX + t;
        float rM = rowMsh[r];
        float rs = 0.0f;
#pragma unroll
        for (int k = 0; k < 16; k++) {
            float v = sp[k * 256];
            rs += __expf(v - rM);
            csum[k] += __expf(v - cmx[k]);
        }
        for (int off = 32; off; off >>= 1) rs += __shfl_xor(rs, off, 64);
        if (lane == 0) rpart[r][w] = rs;
    }
    __syncthreads();
    if (t < 32) {
        float l = rpart[t][0] + rpart[t][1] + rpart[t][2] + rpart[t][3];
        rowli[r0 + t] = 1.0f / l;
    }
#pragma unroll
    for (int k = 0; k < 16; k++) {
        pcm[(size_t)blockIdx.x * NPIX + t + k * 256] = cmx[k];
        pcl[(size_t)blockIdx.x * NPIX + t + k * 256] = csum[k];
    }
}

// combine 128 col partials. grid (16)
__global__ __launch_bounds__(256) void colcomb_kernel(
    const float* __restrict__ pcm, const float* __restrict__ pcl,
    float* __restrict__ cm, float* __restrict__ cli)
{
    int col = blockIdx.x * 256 + threadIdx.x;
    float m = -1e30f, l = 0.0f;
    for (int i = 0; i < 128; i++) {
        float m2 = pcm[(size_t)i * NPIX + col];
        float l2 = pcl[(size_t)i * NPIX + col];
        float mn = fmaxf(m, m2);
        l = l * __expf(m - mn) + l2 * __expf(m2 - mn);
        m = mn;
    }
    cm[col]  = m;
    cli[col] = 1.0f / l;
}

// ---------------- P materialization ----------------
__global__ __launch_bounds__(256) void expP_kernel(
    const float* __restrict__ S, int n_off,
    const float* __restrict__ rowm, const float* __restrict__ rowli,
    const float* __restrict__ colm, const float* __restrict__ colli,
    short* __restrict__ P1, short* __restrict__ P2)
{
    const int row = blockIdx.x;
    const int n = n_off + row;
    const float rm = rowm[n], rl = rowli[n];
    const float* sp = S + (size_t)n * NPIX;
    short* p1 = P1 + (size_t)row * NPIX;
    short* p2 = P2 + (size_t)row * NPIX;
    const int t = threadIdx.x;
#pragma unroll
    for (int i = 0; i < 4; i++) {
        int idx = (i * 256 + t) * 4;
        float4 s4  = *(const float4*)(sp + idx);
        float4 cm4 = *(const float4*)(colm + idx);
        float4 cl4 = *(const float4*)(colli + idx);
        short4v a, bvv;
        a.x = f2bf(__expf(s4.x - rm) * rl);
        a.y = f2bf(__expf(s4.y - rm) * rl);
        a.z = f2bf(__expf(s4.z - rm) * rl);
        a.w = f2bf(__expf(s4.w - rm) * rl);
        bvv.x = f2bf(__expf(s4.x - cm4.x) * cl4.x);
        bvv.y = f2bf(__expf(s4.y - cm4.y) * cl4.y);
        bvv.z = f2bf(__expf(s4.z - cm4.z) * cl4.z);
        bvv.w = f2bf(__expf(s4.w - cm4.w) * cl4.w);
        *(short4v*)(p1 + idx) = a;
        *(short4v*)(p2 + idx) = bvv;
    }
}

// ---------------- Y = P @ Vt^T (deep-K bf16 GEMM, pipelined) ----------------
__global__ __launch_bounds__(256) void ygemm_kernel(
    const short* __restrict__ P1a, const short* __restrict__ P1b,
    const short* __restrict__ P2a, const short* __restrict__ P2b,
    const short* __restrict__ Vt,
    short* __restrict__ Y1s, short* __restrict__ Y2s)
{
    __shared__ short LA[64 * YST], LB[64 * YST];
    const int mode = blockIdx.z;
    const int n0 = blockIdx.y * 64;
    const int c0 = blockIdx.x * 64;
    const short* Pa_ = mode ? P2a : P1a;
    const short* Pb_ = mode ? P2b : P1b;
    const short* A = (n0 < 2048) ? (Pa_ + (size_t)n0 * NPIX)
                                 : (Pb_ + (size_t)(n0 - 2048) * NPIX);
    const short* B = Vt + (size_t)c0 * NPIX;

    const int t = threadIdx.x, lane = t & 63, w = t >> 6;
    const int l31 = lane & 31, l5 = lane >> 5;
    const int nst = (w & 1) * 32, cst = (w >> 1) * 32;
    const int sr = t >> 3;
    const int sk = (t & 7) * 8;

    bf16x8 ra0 = *(const bf16x8*)(A + (size_t)sr * NPIX + sk);
    bf16x8 ra1 = *(const bf16x8*)(A + (size_t)(32 + sr) * NPIX + sk);
    bf16x8 rb0 = *(const bf16x8*)(B + (size_t)sr * NPIX + sk);
    bf16x8 rb1 = *(const bf16x8*)(B + (size_t)(32 + sr) * NPIX + sk);

    f32x16 acc = {};
    for (int k0 = 0; k0 < NPIX; k0 += 64) {
        __syncthreads();
        *(bf16x8*)&LA[sr * YST + sk]        = ra0;
        *(bf16x8*)&LA[(32 + sr) * YST + sk] = ra1;
        *(bf16x8*)&LB[sr * YST + sk]        = rb0;
        *(bf16x8*)&LB[(32 + sr) * YST + sk] = rb1;
        __syncthreads();
        if (k0 + 64 < NPIX) {
            size_t g = (size_t)k0 + 64 + sk;
            ra0 = *(const bf16x8*)(A + (size_t)sr * NPIX + g);
            ra1 = *(const bf16x8*)(A + (size_t)(32 + sr) * NPIX + g);
            rb0 = *(const bf16x8*)(B + (size_t)sr * NPIX + g);
            rb1 = *(const bf16x8*)(B + (size_t)(32 + sr) * NPIX + g);
        }
#pragma unroll
        for (int kc = 0; kc < 4; kc++) {
            bf16x8 af = *(const bf16x8*)&LA[(nst + l31) * YST + kc * 16 + l5 * 8];
            bf16x8 bf = *(const bf16x8*)&LB[(cst + l31) * YST + kc * 16 + l5 * 8];
            acc = __builtin_amdgcn_mfma_f32_32x32x16_bf16(af, bf, acc, 0, 0, 0);
        }
    }
    short* Y = mode ? Y2s : Y1s;
#pragma unroll
    for (int r = 0; r < 16; r++) {
        int rr = cdrow(r, l5);
        Y[(size_t)(n0 + nst + rr) * CC + c0 + cst + l31] = f2bf(acc[r]);
    }
}

extern "C" void kernel_launch(void* const* d_in, const int* in_sizes, int n_in,
                              void* d_out, int out_size, void* d_ws, size_t ws_size,
                              hipStream_t stream)
{
    (void)in_sizes; (void)n_in; (void)out_size; (void)ws_size;
    const float* x      = (const float*)d_in[0];
    const float* w_teta = (const float*)d_in[1];
    const float* b_teta = (const float*)d_in[2];
    const float* w_fi   = (const float*)d_in[3];
    const float* b_fi   = (const float*)d_in[4];
    const float* w_gi   = (const float*)d_in[5];
    const float* b_gi   = (const float*)d_in[6];
    const float* w_o1   = (const float*)d_in[7];
    const float* b_o1   = (const float*)d_in[8];
    const float* w_o2   = (const float*)d_in[9];
    const float* b_o2   = (const float*)d_in[10];
    float* out = (float*)d_out;

    const size_t CN = (size_t)CC * NPIX;       // 1M elements
    const size_t HALF = (size_t)2048 * NPIX;   // 8M shorts = 16 MB
    float* ws    = (float*)d_ws;
    // --- persistent regions ---
    float* S     = ws;                          // 64 MB
    short* Pfr   = (short*)(S + (size_t)NPIX * NPIX);  // 32 MB (P1a+P2a)
    short* x1hi  = Pfr + 2 * HALF;              // 8 MB each
    short* x1lo  = x1hi + BB * CN;
    short* x2thi = x1lo + BB * CN;
    short* x2tlo = x2thi + BB * CN;
    short* Vtb   = x2tlo + BB * CN;             // 8 MB
    short* Y1s   = Vtb + BB * CN;               // 2 MB
    short* Y2s   = Y1s + CN;                    // 2 MB
    float* rowm  = (float*)(Y2s + CN);
    float* rowli = rowm + NPIX;
    float* cm    = rowli + NPIX;
    float* cli   = cm + NPIX;
    float* pcm   = cli + NPIX;                  // 128*NPIX = 2 MB
    float* pcl   = pcm + 128 * NPIX;            // 2 MB
    short* wphi  = (short*)(pcl + 128 * NPIX);  // 3*65536
    short* wplo  = wphi + 3 * 65536;
    short* wob   = wplo + 3 * 65536;            // 2*65536
    // --- aliases ---
    short* xthi = (short*)S;                    // pre-phase only (16 MB in S)
    short* xtlo = xthi + BB * CN;
    float* x2   = (float*)Pfr;                  // pre-phase only (16 MB)
    short* x3b  = (short*)(x2 + BB * CN);       // pre-phase only (8 MB)
    // P halves: a-halves in Pfr, b-halves overwrite S's first 32 MB
    short* P1a = Pfr;
    short* P2a = Pfr + HALF;
    short* P1b = (short*)S;
    short* P2b = (short*)S + HALF;

    dim3 blk(256);
    pack_w_hilo<<<dim3(64, 3), blk, 0, stream>>>(w_teta, w_fi, w_gi, wphi, wplo);
    pack_w_out<<<dim3(64, 2), blk, 0, stream>>>(w_o1, w_o2, wob);
    pack_t_split<<<dim3(128, 8, 4), blk, 0, stream>>>(x, xthi, xtlo);

    proj_mfma<<<dim3(32, 2, 12), blk, 0, stream>>>(
        wphi, wplo, xthi, xtlo, b_teta, b_fi, b_gi, x1hi, x1lo, x2, x3b);

    pack_t_split<<<dim3(128, 8, 4), blk, 0, stream>>>(x2, x2thi, x2tlo);
    packVt_bf<<<dim3(128, 8, 4), blk, 0, stream>>>(x3b, Vtb);

    for (int b = 0; b < BB; b++) {
        scores_mfma<<<dim3(32, 32), blk, 0, stream>>>(
            x1hi + b * CN, x1lo + b * CN, x2thi + b * CN, x2tlo + b * CN, S);
        stats_fused<<<dim3(128), blk, 0, stream>>>(S, rowm, rowli, pcm, pcl);
        colcomb_kernel<<<dim3(16), blk, 0, stream>>>(pcm, pcl, cm, cli);
        expP_kernel<<<dim3(2048), blk, 0, stream>>>(S, 0, rowm, rowli, cm, cli, P1a, P2a);
        expP_kernel<<<dim3(2048), blk, 0, stream>>>(S, 2048, rowm, rowli, cm, cli, P1b, P2b);
        ygemm_kernel<<<dim3(4, 64, 2), blk, 0, stream>>>(
            P1a, P1b, P2a, P2b, Vtb + b * CN, Y1s, Y2s);
        out_mfma<<<dim3(32, 4), blk, 0, stream>>>(
            wob, b_o1, b_o2, Y1s, Y2s, x, out, b);
    }
}

// Round 8
// 676.721 us; speedup vs baseline: 1.2056x; 1.2056x over previous
//
#include <hip/hip_runtime.h>

#define BB   4
#define CC   256
#define NPIX 4096
#define AST2 40    // mfma-core LDS row stride (shorts), 80 B, 16B-aligned
#define YST  72    // ygemm LDS row stride (shorts), 144 B, 16B-aligned

typedef __attribute__((ext_vector_type(8)))  short bf16x8;
typedef __attribute__((ext_vector_type(4)))  short short4v;
typedef __attribute__((ext_vector_type(16))) float f32x16;

__device__ __forceinline__ short f2bf(float f) {
    unsigned u = __float_as_uint(f);
    u = u + 0x7fff + ((u >> 16) & 1);   // RNE
    return (short)(u >> 16);
}
__device__ __forceinline__ float bf2f(short s) {
    return __uint_as_float(((unsigned)(unsigned short)s) << 16);
}
__device__ __forceinline__ void split_bf(float v, short& hi, short& lo) {
    hi = f2bf(v);
    lo = f2bf(v - bf2f(hi));
}
__device__ __forceinline__ int cdrow(int r, int l5) {
    return (r & 3) + 8 * (r >> 2) + 4 * l5;   // verified m74/m101 C/D row map
}

// ---------------------------------------------------------------------------
// hi/lo split-bf16 MFMA core: 128x128 tile, K=256, register-prefetch pipelined.
// ---------------------------------------------------------------------------
__device__ __forceinline__ void mfma_core_hilo(
    const short* __restrict__ Ahi, const short* __restrict__ Alo,
    const short* __restrict__ Bhi, const short* __restrict__ Blo,
    f32x16 acc[2][2])
{
    __shared__ short LAh[128 * AST2], LAl[128 * AST2];
    __shared__ short LBh[128 * AST2], LBl[128 * AST2];
    const int t = threadIdx.x;
    const int lane = t & 63, w = t >> 6;
    const int l31 = lane & 31, l5 = lane >> 5;
    const int nq = (w & 1) * 64, mq = (w >> 1) * 64;
    const int sr = t >> 1;
    const int sk = (t & 1) * 16;
    const size_t gs = (size_t)sr * 256 + sk;
    const int ls = sr * AST2 + sk;

    bf16x8 rAh0 = *(const bf16x8*)(Ahi + gs);
    bf16x8 rAh1 = *(const bf16x8*)(Ahi + gs + 8);
    bf16x8 rAl0 = *(const bf16x8*)(Alo + gs);
    bf16x8 rAl1 = *(const bf16x8*)(Alo + gs + 8);
    bf16x8 rBh0 = *(const bf16x8*)(Bhi + gs);
    bf16x8 rBh1 = *(const bf16x8*)(Bhi + gs + 8);
    bf16x8 rBl0 = *(const bf16x8*)(Blo + gs);
    bf16x8 rBl1 = *(const bf16x8*)(Blo + gs + 8);

    for (int k0 = 0; k0 < 256; k0 += 32) {
        __syncthreads();
        *(bf16x8*)&LAh[ls]     = rAh0;
        *(bf16x8*)&LAh[ls + 8] = rAh1;
        *(bf16x8*)&LAl[ls]     = rAl0;
        *(bf16x8*)&LAl[ls + 8] = rAl1;
        *(bf16x8*)&LBh[ls]     = rBh0;
        *(bf16x8*)&LBh[ls + 8] = rBh1;
        *(bf16x8*)&LBl[ls]     = rBl0;
        *(bf16x8*)&LBl[ls + 8] = rBl1;
        __syncthreads();
        if (k0 + 32 < 256) {
            size_t g = gs + k0 + 32;
            rAh0 = *(const bf16x8*)(Ahi + g);
            rAh1 = *(const bf16x8*)(Ahi + g + 8);
            rAl0 = *(const bf16x8*)(Alo + g);
            rAl1 = *(const bf16x8*)(Alo + g + 8);
            rBh0 = *(const bf16x8*)(Bhi + g);
            rBh1 = *(const bf16x8*)(Bhi + g + 8);
            rBl0 = *(const bf16x8*)(Blo + g);
            rBl1 = *(const bf16x8*)(Blo + g + 8);
        }
#pragma unroll
        for (int ks = 0; ks < 2; ks++) {
            bf16x8 ah[2], al[2], bh[2], bl[2];
#pragma unroll
            for (int s = 0; s < 2; s++) {
                int ra = (nq + s * 32 + l31) * AST2 + ks * 16 + l5 * 8;
                int rb = (mq + s * 32 + l31) * AST2 + ks * 16 + l5 * 8;
                ah[s] = *(const bf16x8*)&LAh[ra];
                al[s] = *(const bf16x8*)&LAl[ra];
                bh[s] = *(const bf16x8*)&LBh[rb];
                bl[s] = *(const bf16x8*)&LBl[rb];
            }
#pragma unroll
            for (int s = 0; s < 2; s++)
#pragma unroll
                for (int u = 0; u < 2; u++) {
                    acc[s][u] = __builtin_amdgcn_mfma_f32_32x32x16_bf16(ah[s], bh[u], acc[s][u], 0, 0, 0);
                    acc[s][u] = __builtin_amdgcn_mfma_f32_32x32x16_bf16(ah[s], bl[u], acc[s][u], 0, 0, 0);
                    acc[s][u] = __builtin_amdgcn_mfma_f32_32x32x16_bf16(al[s], bh[u], acc[s][u], 0, 0, 0);
                }
        }
    }
}

// Single-bf16 variant (output GEMM), pipelined.
__device__ __forceinline__ void mfma_core_single(
    const short* __restrict__ A, const short* __restrict__ B, f32x16 acc[2][2])
{
    __shared__ short LA[128 * AST2], LB[128 * AST2];
    const int t = threadIdx.x;
    const int lane = t & 63, w = t >> 6;
    const int l31 = lane & 31, l5 = lane >> 5;
    const int nq = (w & 1) * 64, mq = (w >> 1) * 64;
    const int sr = t >> 1;
    const int sk = (t & 1) * 16;
    const size_t gs = (size_t)sr * 256 + sk;
    const int ls = sr * AST2 + sk;

    bf16x8 rA0 = *(const bf16x8*)(A + gs);
    bf16x8 rA1 = *(const bf16x8*)(A + gs + 8);
    bf16x8 rB0 = *(const bf16x8*)(B + gs);
    bf16x8 rB1 = *(const bf16x8*)(B + gs + 8);

    for (int k0 = 0; k0 < 256; k0 += 32) {
        __syncthreads();
        *(bf16x8*)&LA[ls]     = rA0;
        *(bf16x8*)&LA[ls + 8] = rA1;
        *(bf16x8*)&LB[ls]     = rB0;
        *(bf16x8*)&LB[ls + 8] = rB1;
        __syncthreads();
        if (k0 + 32 < 256) {
            size_t g = gs + k0 + 32;
            rA0 = *(const bf16x8*)(A + g);
            rA1 = *(const bf16x8*)(A + g + 8);
            rB0 = *(const bf16x8*)(B + g);
            rB1 = *(const bf16x8*)(B + g + 8);
        }
#pragma unroll
        for (int ks = 0; ks < 2; ks++) {
            bf16x8 a[2], b[2];
#pragma unroll
            for (int s = 0; s < 2; s++) {
                a[s] = *(const bf16x8*)&LA[(nq + s * 32 + l31) * AST2 + ks * 16 + l5 * 8];
                b[s] = *(const bf16x8*)&LB[(mq + s * 32 + l31) * AST2 + ks * 16 + l5 * 8];
            }
#pragma unroll
            for (int s = 0; s < 2; s++)
#pragma unroll
                for (int u = 0; u < 2; u++)
                    acc[s][u] = __builtin_amdgcn_mfma_f32_32x32x16_bf16(a[s], b[u], acc[s][u], 0, 0, 0);
        }
    }
}

// ---------------- pack kernels ----------------

__global__ __launch_bounds__(256) void pack_w_hilo(
    const float* __restrict__ w0, const float* __restrict__ w1, const float* __restrict__ w2,
    short* __restrict__ whi, short* __restrict__ wlo)
{
    int which = blockIdx.y;
    const float* w = which == 0 ? w0 : which == 1 ? w1 : w2;
    int idx = blockIdx.x * 1024 + threadIdx.x * 4;
    float4 v = *(const float4*)(w + idx);
    short4v h, l;
    short th, tl;
    split_bf(v.x, th, tl); h.x = th; l.x = tl;
    split_bf(v.y, th, tl); h.y = th; l.y = tl;
    split_bf(v.z, th, tl); h.z = th; l.z = tl;
    split_bf(v.w, th, tl); h.w = th; l.w = tl;
    *(short4v*)(whi + which * 65536 + idx) = h;
    *(short4v*)(wlo + which * 65536 + idx) = l;
}

__global__ __launch_bounds__(256) void pack_w_out(
    const float* __restrict__ w1, const float* __restrict__ w2, short* __restrict__ wob)
{
    int which = blockIdx.y;
    const float* w = which == 0 ? w1 : w2;
    int idx = blockIdx.x * 1024 + threadIdx.x * 4;
    float4 v = *(const float4*)(w + idx);
    short4v h;
    h.x = f2bf(v.x); h.y = f2bf(v.y); h.z = f2bf(v.z); h.w = f2bf(v.w);
    *(short4v*)(wob + which * 65536 + idx) = h;
}

// transpose + split: [b][256][4096] fp32 -> [b][4096][256] hi/lo bf16. grid (128,8,4)
__global__ __launch_bounds__(256) void pack_t_split(
    const float* __restrict__ in, short* __restrict__ ohi, short* __restrict__ olo)
{
    __shared__ short Th[32][36], Tl[32][36];
    const int b  = blockIdx.z;
    const int n0 = blockIdx.x * 32;
    const int c0 = blockIdx.y * 32;
    const float* src = in + (size_t)b * CC * NPIX;
    const int t = threadIdx.x;
    const int r = t >> 3, q = t & 7;
    float4 v = *(const float4*)(src + (size_t)(c0 + r) * NPIX + n0 + q * 4);
    short h, l;
    split_bf(v.x, h, l); Th[q * 4 + 0][r] = h; Tl[q * 4 + 0][r] = l;
    split_bf(v.y, h, l); Th[q * 4 + 1][r] = h; Tl[q * 4 + 1][r] = l;
    split_bf(v.z, h, l); Th[q * 4 + 2][r] = h; Tl[q * 4 + 2][r] = l;
    split_bf(v.w, h, l); Th[q * 4 + 3][r] = h; Tl[q * 4 + 3][r] = l;
    __syncthreads();
    short4v oh, ol;
    oh.x = Th[r][q * 4 + 0]; ol.x = Tl[r][q * 4 + 0];
    oh.y = Th[r][q * 4 + 1]; ol.y = Tl[r][q * 4 + 1];
    oh.z = Th[r][q * 4 + 2]; ol.z = Tl[r][q * 4 + 2];
    oh.w = Th[r][q * 4 + 3]; ol.w = Tl[r][q * 4 + 3];
    size_t o = (size_t)b * CC * NPIX + (size_t)(n0 + r) * 256 + c0 + q * 4;
    *(short4v*)(ohi + o) = oh;
    *(short4v*)(olo + o) = ol;
}

// Vt[c][m] = x3b.flat[m*256+c] (already bf16). grid (128,8,4)
__global__ __launch_bounds__(256) void packVt_bf(
    const short* __restrict__ x3b, short* __restrict__ Vt)
{
    __shared__ short T[32][33];
    const int b  = blockIdx.z;
    const int m0 = blockIdx.x * 32;
    const int c0 = blockIdx.y * 32;
    const short* in = x3b + (size_t)b * CC * NPIX;
    short* out = Vt + (size_t)b * CC * NPIX;
    const int t = threadIdx.x;
    const int r = t >> 3, q = t & 7;
    short4v v = *(const short4v*)(in + (size_t)(m0 + r) * CC + c0 + q * 4);
    T[q * 4 + 0][r] = v.x;
    T[q * 4 + 1][r] = v.y;
    T[q * 4 + 2][r] = v.z;
    T[q * 4 + 3][r] = v.w;
    __syncthreads();
    short4v o;
    o.x = T[r][q * 4 + 0];
    o.y = T[r][q * 4 + 1];
    o.z = T[r][q * 4 + 2];
    o.w = T[r][q * 4 + 3];
    *(short4v*)(out + (size_t)(c0 + r) * NPIX + m0 + q * 4) = o;
}

// ---------------- GEMM kernels ----------------

// proj. grid (32, 2, 12). p=0 -> x1 hi/lo, p=1 -> x2 fp32, p=2 -> x3 bf16.
__global__ __launch_bounds__(256) void proj_mfma(
    const short* __restrict__ wphi, const short* __restrict__ wplo,
    const short* __restrict__ xthi, const short* __restrict__ xtlo,
    const float* __restrict__ b_teta, const float* __restrict__ b_fi,
    const float* __restrict__ b_gi,
    short* __restrict__ x1hi, short* __restrict__ x1lo,
    float* __restrict__ x2, short* __restrict__ x3b)
{
    const int z = blockIdx.z, p = z >> 2, b = z & 3;
    const int n0 = blockIdx.x * 128, c0 = blockIdx.y * 128;
    const size_t CN = (size_t)CC * NPIX;
    const short* Ah = wphi + p * 65536 + c0 * 256;
    const short* Al = wplo + p * 65536 + c0 * 256;
    const short* Bh = xthi + (size_t)b * CN + (size_t)n0 * 256;
    const short* Bl = xtlo + (size_t)b * CN + (size_t)n0 * 256;
    const float* bias = p == 0 ? b_teta : p == 1 ? b_fi : b_gi;

    f32x16 acc[2][2] = {};
    mfma_core_hilo(Ah, Al, Bh, Bl, acc);

    const int t = threadIdx.x, lane = t & 63, w = t >> 6;
    const int l31 = lane & 31, l5 = lane >> 5;
    const int aq = (w & 1) * 64, bq = (w >> 1) * 64;
#pragma unroll
    for (int s = 0; s < 2; s++)
#pragma unroll
        for (int u = 0; u < 2; u++)
#pragma unroll
            for (int r = 0; r < 16; r++) {
                int c = c0 + aq + s * 32 + cdrow(r, l5);
                int n = n0 + bq + u * 32 + l31;
                float v = acc[s][u][r] + bias[c];
                size_t o = (size_t)b * CN + (size_t)c * NPIX + n;
                if (p == 0) {
                    short h, l; split_bf(v, h, l);
                    x1hi[o] = h; x1lo[o] = l;
                } else if (p == 1) {
                    x2[o] = v;
                } else {
                    x3b[o] = f2bf(v);
                }
            }
}

// scores. grid (32, 32) per batch
__global__ __launch_bounds__(256) void scores_mfma(
    const short* __restrict__ x1hi, const short* __restrict__ x1lo,
    const short* __restrict__ x2thi, const short* __restrict__ x2tlo,
    float* __restrict__ S)
{
    const int m0 = blockIdx.x * 128, n0 = blockIdx.y * 128;
    f32x16 acc[2][2] = {};
    mfma_core_hilo(x1hi + (size_t)n0 * 256, x1lo + (size_t)n0 * 256,
                   x2thi + (size_t)m0 * 256, x2tlo + (size_t)m0 * 256, acc);

    const int t = threadIdx.x, lane = t & 63, w = t >> 6;
    const int l31 = lane & 31, l5 = lane >> 5;
    const int aq = (w & 1) * 64, bq = (w >> 1) * 64;
#pragma unroll
    for (int s = 0; s < 2; s++)
#pragma unroll
        for (int u = 0; u < 2; u++)
#pragma unroll
            for (int r = 0; r < 16; r++) {
                int n = n0 + aq + s * 32 + cdrow(r, l5);
                int m = m0 + bq + u * 32 + l31;
                S[(size_t)n * NPIX + m] = acc[s][u][r];
            }
}

// out: relu(x + bias + W.Y^T), single batch. grid (32, 4)
__global__ __launch_bounds__(256) void out_mfma(
    const short* __restrict__ wob,
    const float* __restrict__ b_o1, const float* __restrict__ b_o2,
    const short* __restrict__ Y1s, const short* __restrict__ Y2s,
    const float* __restrict__ x, float* __restrict__ out, int b)
{
    const int ch0 = blockIdx.y * 128;
    const int pix0 = blockIdx.x * 128;
    const short* W = wob + (ch0 < 256 ? 0 : 65536) + (size_t)(ch0 & 255) * 256;
    const short* Y = (ch0 < 256 ? Y1s : Y2s) + (size_t)pix0 * 256;
    const float* bias = ch0 < 256 ? b_o1 : b_o2;

    f32x16 acc[2][2] = {};
    mfma_core_single(W, Y, acc);

    const int t = threadIdx.x, lane = t & 63, w = t >> 6;
    const int l31 = lane & 31, l5 = lane >> 5;
    const int aq = (w & 1) * 64, bq = (w >> 1) * 64;
#pragma unroll
    for (int s = 0; s < 2; s++)
#pragma unroll
        for (int u = 0; u < 2; u++)
#pragma unroll
            for (int r = 0; r < 16; r++) {
                int ch = ch0 + aq + s * 32 + cdrow(r, l5);
                int pix = pix0 + bq + u * 32 + l31;
                int chm = ch & 255;
                float v = acc[s][u][r] + bias[chm] +
                          x[((size_t)b * CC + chm) * NPIX + pix];
                out[((size_t)b * 2 * CC + ch) * NPIX + pix] = fmaxf(v, 0.0f);
            }
}

// ---------------- column softmax stats (round-6 known good) ----------------

__global__ __launch_bounds__(256) void colstats1_kernel(
    const float* __restrict__ S, float* __restrict__ pm, float* __restrict__ pl)
{
    int col = blockIdx.x * 256 + threadIdx.x;
    int r0  = blockIdx.y * 128;
    float m = -1e30f, l = 0.0f;
    for (int r = 0; r < 128; r++) {
        float v = S[(size_t)(r0 + r) * NPIX + col];
        float mn = fmaxf(m, v);
        l = l * __expf(m - mn) + __expf(v - mn);
        m = mn;
    }
    pm[(size_t)blockIdx.y * NPIX + col] = m;
    pl[(size_t)blockIdx.y * NPIX + col] = l;
}

__global__ __launch_bounds__(256) void colstats2_kernel(
    const float* __restrict__ pm, const float* __restrict__ pl,
    float* __restrict__ cm, float* __restrict__ cli)
{
    int col = blockIdx.x * 256 + threadIdx.x;
    float m = -1e30f, l = 0.0f;
    for (int i = 0; i < 32; i++) {
        float m2 = pm[(size_t)i * NPIX + col];
        float l2 = pl[(size_t)i * NPIX + col];
        float mn = fmaxf(m, m2);
        l = l * __expf(m - mn) + l2 * __expf(m2 - mn);
        m = mn;
    }
    cm[col]  = m;
    cli[col] = 1.0f / l;
}

// ---------------- fused row-stats + P materialization ----------------
// One block per S row. Row held in registers (16 floats/thread): compute
// row max + sum, then write P1 (row softmax) and P2 (col softmax) bf16.
__global__ __launch_bounds__(256) void rowexpP_kernel(
    const float* __restrict__ S, int n_off,
    const float* __restrict__ colm, const float* __restrict__ colli,
    short* __restrict__ P1, short* __restrict__ P2)
{
    const int row = blockIdx.x;
    const int n = n_off + row;
    const float* sp = S + (size_t)n * NPIX;
    const int t = threadIdx.x;
    const int w = t >> 6, lane = t & 63;
    __shared__ float red[4];

    float4 s4[4];
#pragma unroll
    for (int i = 0; i < 4; i++)
        s4[i] = *(const float4*)(sp + (i * 256 + t) * 4);

    // row max
    float m = -1e30f;
#pragma unroll
    for (int i = 0; i < 4; i++) {
        m = fmaxf(m, fmaxf(fmaxf(s4[i].x, s4[i].y), fmaxf(s4[i].z, s4[i].w)));
    }
    for (int off = 32; off; off >>= 1) m = fmaxf(m, __shfl_xor(m, off, 64));
    if (lane == 0) red[w] = m;
    __syncthreads();
    m = fmaxf(fmaxf(red[0], red[1]), fmaxf(red[2], red[3]));
    __syncthreads();

    // row sum of exp
    float e[16];
    float sum = 0.0f;
#pragma unroll
    for (int i = 0; i < 4; i++) {
        e[i * 4 + 0] = __expf(s4[i].x - m);
        e[i * 4 + 1] = __expf(s4[i].y - m);
        e[i * 4 + 2] = __expf(s4[i].z - m);
        e[i * 4 + 3] = __expf(s4[i].w - m);
        sum += e[i * 4 + 0] + e[i * 4 + 1] + e[i * 4 + 2] + e[i * 4 + 3];
    }
    for (int off = 32; off; off >>= 1) sum += __shfl_xor(sum, off, 64);
    if (lane == 0) red[w] = sum;
    __syncthreads();
    float rl = 1.0f / (red[0] + red[1] + red[2] + red[3]);

    short* p1 = P1 + (size_t)row * NPIX;
    short* p2 = P2 + (size_t)row * NPIX;
#pragma unroll
    for (int i = 0; i < 4; i++) {
        int idx = (i * 256 + t) * 4;
        float4 cm4 = *(const float4*)(colm + idx);
        float4 cl4 = *(const float4*)(colli + idx);
        short4v a, bvv;
        a.x = f2bf(e[i * 4 + 0] * rl);
        a.y = f2bf(e[i * 4 + 1] * rl);
        a.z = f2bf(e[i * 4 + 2] * rl);
        a.w = f2bf(e[i * 4 + 3] * rl);
        bvv.x = f2bf(__expf(s4[i].x - cm4.x) * cl4.x);
        bvv.y = f2bf(__expf(s4[i].y - cm4.y) * cl4.y);
        bvv.z = f2bf(__expf(s4[i].z - cm4.z) * cl4.z);
        bvv.w = f2bf(__expf(s4[i].w - cm4.w) * cl4.w);
        *(short4v*)(p1 + idx) = a;
        *(short4v*)(p2 + idx) = bvv;
    }
}

// ---------------- Y = P @ Vt^T (deep-K bf16 GEMM, pipelined) ----------------
__global__ __launch_bounds__(256) void ygemm_kernel(
    const short* __restrict__ P1a, const short* __restrict__ P1b,
    const short* __restrict__ P2a, const short* __restrict__ P2b,
    const short* __restrict__ Vt,
    short* __restrict__ Y1s, short* __restrict__ Y2s)
{
    __shared__ short LA[64 * YST], LB[64 * YST];
    const int mode = blockIdx.z;
    const int n0 = blockIdx.y * 64;
    const int c0 = blockIdx.x * 64;
    const short* Pa_ = mode ? P2a : P1a;
    const short* Pb_ = mode ? P2b : P1b;
    const short* A = (n0 < 2048) ? (Pa_ + (size_t)n0 * NPIX)
                                 : (Pb_ + (size_t)(n0 - 2048) * NPIX);
    const short* B = Vt + (size_t)c0 * NPIX;

    const int t = threadIdx.x, lane = t & 63, w = t >> 6;
    const int l31 = lane & 31, l5 = lane >> 5;
    const int nst = (w & 1) * 32, cst = (w >> 1) * 32;
    const int sr = t >> 3;
    const int sk = (t & 7) * 8;

    bf16x8 ra0 = *(const bf16x8*)(A + (size_t)sr * NPIX + sk);
    bf16x8 ra1 = *(const bf16x8*)(A + (size_t)(32 + sr) * NPIX + sk);
    bf16x8 rb0 = *(const bf16x8*)(B + (size_t)sr * NPIX + sk);
    bf16x8 rb1 = *(const bf16x8*)(B + (size_t)(32 + sr) * NPIX + sk);

    f32x16 acc = {};
    for (int k0 = 0; k0 < NPIX; k0 += 64) {
        __syncthreads();
        *(bf16x8*)&LA[sr * YST + sk]        = ra0;
        *(bf16x8*)&LA[(32 + sr) * YST + sk] = ra1;
        *(bf16x8*)&LB[sr * YST + sk]        = rb0;
        *(bf16x8*)&LB[(32 + sr) * YST + sk] = rb1;
        __syncthreads();
        if (k0 + 64 < NPIX) {
            size_t g = (size_t)k0 + 64 + sk;
            ra0 = *(const bf16x8*)(A + (size_t)sr * NPIX + g);
            ra1 = *(const bf16x8*)(A + (size_t)(32 + sr) * NPIX + g);
            rb0 = *(const bf16x8*)(B + (size_t)sr * NPIX + g);
            rb1 = *(const bf16x8*)(B + (size_t)(32 + sr) * NPIX + g);
        }
#pragma unroll
        for (int kc = 0; kc < 4; kc++) {
            bf16x8 af = *(const bf16x8*)&LA[(nst + l31) * YST + kc * 16 + l5 * 8];
            bf16x8 bf = *(const bf16x8*)&LB[(cst + l31) * YST + kc * 16 + l5 * 8];
            acc = __builtin_amdgcn_mfma_f32_32x32x16_bf16(af, bf, acc, 0, 0, 0);
        }
    }
    short* Y = mode ? Y2s : Y1s;
#pragma unroll
    for (int r = 0; r < 16; r++) {
        int rr = cdrow(r, l5);
        Y[(size_t)(n0 + nst + rr) * CC + c0 + cst + l31] = f2bf(acc[r]);
    }
}

extern "C" void kernel_launch(void* const* d_in, const int* in_sizes, int n_in,
                              void* d_out, int out_size, void* d_ws, size_t ws_size,
                              hipStream_t stream)
{
    (void)in_sizes; (void)n_in; (void)out_size; (void)ws_size;
    const float* x      = (const float*)d_in[0];
    const float* w_teta = (const float*)d_in[1];
    const float* b_teta = (const float*)d_in[2];
    const float* w_fi   = (const float*)d_in[3];
    const float* b_fi   = (const float*)d_in[4];
    const float* w_gi   = (const float*)d_in[5];
    const float* b_gi   = (const float*)d_in[6];
    const float* w_o1   = (const float*)d_in[7];
    const float* b_o1   = (const float*)d_in[8];
    const float* w_o2   = (const float*)d_in[9];
    const float* b_o2   = (const float*)d_in[10];
    float* out = (float*)d_out;

    const size_t CN = (size_t)CC * NPIX;       // 1M elements
    const size_t HALF = (size_t)2048 * NPIX;   // 8M shorts = 16 MB
    float* ws    = (float*)d_ws;
    // --- persistent regions ---
    float* S     = ws;                          // 64 MB
    short* Pfr   = (short*)(S + (size_t)NPIX * NPIX);  // 32 MB (P1a+P2a)
    short* x1hi  = Pfr + 2 * HALF;              // 8 MB each
    short* x1lo  = x1hi + BB * CN;
    short* x2thi = x1lo + BB * CN;
    short* x2tlo = x2thi + BB * CN;
    short* Vtb   = x2tlo + BB * CN;             // 8 MB
    short* Y1s   = Vtb + BB * CN;               // 2 MB
    short* Y2s   = Y1s + CN;                    // 2 MB
    float* cm    = (float*)(Y2s + CN);
    float* cli   = cm + NPIX;
    float* pm    = cli + NPIX;                  // 32*NPIX
    float* pl    = pm + 32 * NPIX;
    short* wphi  = (short*)(pl + 32 * NPIX);    // 3*65536
    short* wplo  = wphi + 3 * 65536;
    short* wob   = wplo + 3 * 65536;            // 2*65536
    // --- aliases ---
    short* xthi = (short*)S;                    // pre-phase only (16 MB in S)
    short* xtlo = xthi + BB * CN;
    float* x2   = (float*)Pfr;                  // pre-phase only (16 MB)
    short* x3b  = (short*)(x2 + BB * CN);       // pre-phase only (8 MB)
    // P halves: a-halves in Pfr, b-halves overwrite S's first 32 MB
    short* P1a = Pfr;
    short* P2a = Pfr + HALF;
    short* P1b = (short*)S;
    short* P2b = (short*)S + HALF;

    dim3 blk(256);
    pack_w_hilo<<<dim3(64, 3), blk, 0, stream>>>(w_teta, w_fi, w_gi, wphi, wplo);
    pack_w_out<<<dim3(64, 2), blk, 0, stream>>>(w_o1, w_o2, wob);
    pack_t_split<<<dim3(128, 8, 4), blk, 0, stream>>>(x, xthi, xtlo);

    proj_mfma<<<dim3(32, 2, 12), blk, 0, stream>>>(
        wphi, wplo, xthi, xtlo, b_teta, b_fi, b_gi, x1hi, x1lo, x2, x3b);

    pack_t_split<<<dim3(128, 8, 4), blk, 0, stream>>>(x2, x2thi, x2tlo);
    packVt_bf<<<dim3(128, 8, 4), blk, 0, stream>>>(x3b, Vtb);

    for (int b = 0; b < BB; b++) {
        scores_mfma<<<dim3(32, 32), blk, 0, stream>>>(
            x1hi + b * CN, x1lo + b * CN, x2thi + b * CN, x2tlo + b * CN, S);
        colstats1_kernel<<<dim3(16, 32), blk, 0, stream>>>(S, pm, pl);
        colstats2_kernel<<<dim3(16), blk, 0, stream>>>(pm, pl, cm, cli);
        // half 1: rows [0,2048) -> Pfr ; half 2: rows [2048,4096) -> S base
        rowexpP_kernel<<<dim3(2048), blk, 0, stream>>>(S, 0, cm, cli, P1a, P2a);
        rowexpP_kernel<<<dim3(2048), blk, 0, stream>>>(S, 2048, cm, cli, P1b, P2b);
        ygemm_kernel<<<dim3(4, 64, 2), blk, 0, stream>>>(
            P1a, P1b, P2a, P2b, Vtb + b * CN, Y1s, Y2s);
        out_mfma<<<dim3(32, 4), blk, 0, stream>>>(
            wob, b_o1, b_o2, Y1s, Y2s, x, out, b);
    }
}

// Round 10
// 640.695 us; speedup vs baseline: 1.2734x; 1.0562x over previous
//
#include <hip/hip_runtime.h>

#define BB   4
#define CC   256
#define NPIX 4096
#define AST2 40    // mfma-core LDS row stride (shorts), 80 B, 16B-aligned
#define YST2 136   // ygemm LDS row stride (shorts) for K-step 128

typedef __attribute__((ext_vector_type(8)))  short bf16x8;
typedef __attribute__((ext_vector_type(4)))  short short4v;
typedef __attribute__((ext_vector_type(16))) float f32x16;

__device__ __forceinline__ short f2bf(float f) {
    unsigned u = __float_as_uint(f);
    u = u + 0x7fff + ((u >> 16) & 1);   // RNE
    return (short)(u >> 16);
}
__device__ __forceinline__ float bf2f(short s) {
    return __uint_as_float(((unsigned)(unsigned short)s) << 16);
}
__device__ __forceinline__ void split_bf(float v, short& hi, short& lo) {
    hi = f2bf(v);
    lo = f2bf(v - bf2f(hi));
}
__device__ __forceinline__ int cdrow(int r, int l5) {
    return (r & 3) + 8 * (r >> 2) + 4 * l5;   // verified m74/m101 C/D row map
}

// ---------------------------------------------------------------------------
// hi/lo split-bf16 MFMA core: 128x128 tile, K=256, register-prefetch pipelined.
// ---------------------------------------------------------------------------
__device__ __forceinline__ void mfma_core_hilo(
    const short* __restrict__ Ahi, const short* __restrict__ Alo,
    const short* __restrict__ Bhi, const short* __restrict__ Blo,
    f32x16 acc[2][2])
{
    __shared__ short LAh[128 * AST2], LAl[128 * AST2];
    __shared__ short LBh[128 * AST2], LBl[128 * AST2];
    const int t = threadIdx.x;
    const int lane = t & 63, w = t >> 6;
    const int l31 = lane & 31, l5 = lane >> 5;
    const int nq = (w & 1) * 64, mq = (w >> 1) * 64;
    const int sr = t >> 1;
    const int sk = (t & 1) * 16;
    const size_t gs = (size_t)sr * 256 + sk;
    const int ls = sr * AST2 + sk;

    bf16x8 rAh0 = *(const bf16x8*)(Ahi + gs);
    bf16x8 rAh1 = *(const bf16x8*)(Ahi + gs + 8);
    bf16x8 rAl0 = *(const bf16x8*)(Alo + gs);
    bf16x8 rAl1 = *(const bf16x8*)(Alo + gs + 8);
    bf16x8 rBh0 = *(const bf16x8*)(Bhi + gs);
    bf16x8 rBh1 = *(const bf16x8*)(Bhi + gs + 8);
    bf16x8 rBl0 = *(const bf16x8*)(Blo + gs);
    bf16x8 rBl1 = *(const bf16x8*)(Blo + gs + 8);

    for (int k0 = 0; k0 < 256; k0 += 32) {
        __syncthreads();
        *(bf16x8*)&LAh[ls]     = rAh0;
        *(bf16x8*)&LAh[ls + 8] = rAh1;
        *(bf16x8*)&LAl[ls]     = rAl0;
        *(bf16x8*)&LAl[ls + 8] = rAl1;
        *(bf16x8*)&LBh[ls]     = rBh0;
        *(bf16x8*)&LBh[ls + 8] = rBh1;
        *(bf16x8*)&LBl[ls]     = rBl0;
        *(bf16x8*)&LBl[ls + 8] = rBl1;
        __syncthreads();
        if (k0 + 32 < 256) {
            size_t g = gs + k0 + 32;
            rAh0 = *(const bf16x8*)(Ahi + g);
            rAh1 = *(const bf16x8*)(Ahi + g + 8);
            rAl0 = *(const bf16x8*)(Alo + g);
            rAl1 = *(const bf16x8*)(Alo + g + 8);
            rBh0 = *(const bf16x8*)(Bhi + g);
            rBh1 = *(const bf16x8*)(Bhi + g + 8);
            rBl0 = *(const bf16x8*)(Blo + g);
            rBl1 = *(const bf16x8*)(Blo + g + 8);
        }
#pragma unroll
        for (int ks = 0; ks < 2; ks++) {
            bf16x8 ah[2], al[2], bh[2], bl[2];
#pragma unroll
            for (int s = 0; s < 2; s++) {
                int ra = (nq + s * 32 + l31) * AST2 + ks * 16 + l5 * 8;
                int rb = (mq + s * 32 + l31) * AST2 + ks * 16 + l5 * 8;
                ah[s] = *(const bf16x8*)&LAh[ra];
                al[s] = *(const bf16x8*)&LAl[ra];
                bh[s] = *(const bf16x8*)&LBh[rb];
                bl[s] = *(const bf16x8*)&LBl[rb];
            }
#pragma unroll
            for (int s = 0; s < 2; s++)
#pragma unroll
                for (int u = 0; u < 2; u++) {
                    acc[s][u] = __builtin_amdgcn_mfma_f32_32x32x16_bf16(ah[s], bh[u], acc[s][u], 0, 0, 0);
                    acc[s][u] = __builtin_amdgcn_mfma_f32_32x32x16_bf16(ah[s], bl[u], acc[s][u], 0, 0, 0);
                    acc[s][u] = __builtin_amdgcn_mfma_f32_32x32x16_bf16(al[s], bh[u], acc[s][u], 0, 0, 0);
                }
        }
    }
}

// Single-bf16 variant (output GEMM), pipelined.
__device__ __forceinline__ void mfma_core_single(
    const short* __restrict__ A, const short* __restrict__ B, f32x16 acc[2][2])
{
    __shared__ short LA[128 * AST2], LB[128 * AST2];
    const int t = threadIdx.x;
    const int lane = t & 63, w = t >> 6;
    const int l31 = lane & 31, l5 = lane >> 5;
    const int nq = (w & 1) * 64, mq = (w >> 1) * 64;
    const int sr = t >> 1;
    const int sk = (t & 1) * 16;
    const size_t gs = (size_t)sr * 256 + sk;
    const int ls = sr * AST2 + sk;

    bf16x8 rA0 = *(const bf16x8*)(A + gs);
    bf16x8 rA1 = *(const bf16x8*)(A + gs + 8);
    bf16x8 rB0 = *(const bf16x8*)(B + gs);
    bf16x8 rB1 = *(const bf16x8*)(B + gs + 8);

    for (int k0 = 0; k0 < 256; k0 += 32) {
        __syncthreads();
        *(bf16x8*)&LA[ls]     = rA0;
        *(bf16x8*)&LA[ls + 8] = rA1;
        *(bf16x8*)&LB[ls]     = rB0;
        *(bf16x8*)&LB[ls + 8] = rB1;
        __syncthreads();
        if (k0 + 32 < 256) {
            size_t g = gs + k0 + 32;
            rA0 = *(const bf16x8*)(A + g);
            rA1 = *(const bf16x8*)(A + g + 8);
            rB0 = *(const bf16x8*)(B + g);
            rB1 = *(const bf16x8*)(B + g + 8);
        }
#pragma unroll
        for (int ks = 0; ks < 2; ks++) {
            bf16x8 a[2], b[2];
#pragma unroll
            for (int s = 0; s < 2; s++) {
                a[s] = *(const bf16x8*)&LA[(nq + s * 32 + l31) * AST2 + ks * 16 + l5 * 8];
                b[s] = *(const bf16x8*)&LB[(mq + s * 32 + l31) * AST2 + ks * 16 + l5 * 8];
            }
#pragma unroll
            for (int s = 0; s < 2; s++)
#pragma unroll
                for (int u = 0; u < 2; u++)
                    acc[s][u] = __builtin_amdgcn_mfma_f32_32x32x16_bf16(a[s], b[u], acc[s][u], 0, 0, 0);
        }
    }
}

// ---------------- pack kernels ----------------

__global__ __launch_bounds__(256) void pack_w_hilo(
    const float* __restrict__ w0, const float* __restrict__ w1, const float* __restrict__ w2,
    short* __restrict__ whi, short* __restrict__ wlo)
{
    int which = blockIdx.y;
    const float* w = which == 0 ? w0 : which == 1 ? w1 : w2;
    int idx = blockIdx.x * 1024 + threadIdx.x * 4;
    float4 v = *(const float4*)(w + idx);
    short4v h, l;
    short th, tl;
    split_bf(v.x, th, tl); h.x = th; l.x = tl;
    split_bf(v.y, th, tl); h.y = th; l.y = tl;
    split_bf(v.z, th, tl); h.z = th; l.z = tl;
    split_bf(v.w, th, tl); h.w = th; l.w = tl;
    *(short4v*)(whi + which * 65536 + idx) = h;
    *(short4v*)(wlo + which * 65536 + idx) = l;
}

__global__ __launch_bounds__(256) void pack_w_out(
    const float* __restrict__ w1, const float* __restrict__ w2, short* __restrict__ wob)
{
    int which = blockIdx.y;
    const float* w = which == 0 ? w1 : w2;
    int idx = blockIdx.x * 1024 + threadIdx.x * 4;
    float4 v = *(const float4*)(w + idx);
    short4v h;
    h.x = f2bf(v.x); h.y = f2bf(v.y); h.z = f2bf(v.z); h.w = f2bf(v.w);
    *(short4v*)(wob + which * 65536 + idx) = h;
}

// transpose + split: [b][256][4096] fp32 -> [b][4096][256] hi/lo bf16. grid (128,8,4)
__global__ __launch_bounds__(256) void pack_t_split(
    const float* __restrict__ in, short* __restrict__ ohi, short* __restrict__ olo)
{
    __shared__ short Th[32][36], Tl[32][36];
    const int b  = blockIdx.z;
    const int n0 = blockIdx.x * 32;
    const int c0 = blockIdx.y * 32;
    const float* src = in + (size_t)b * CC * NPIX;
    const int t = threadIdx.x;
    const int r = t >> 3, q = t & 7;
    float4 v = *(const float4*)(src + (size_t)(c0 + r) * NPIX + n0 + q * 4);
    short h, l;
    split_bf(v.x, h, l); Th[q * 4 + 0][r] = h; Tl[q * 4 + 0][r] = l;
    split_bf(v.y, h, l); Th[q * 4 + 1][r] = h; Tl[q * 4 + 1][r] = l;
    split_bf(v.z, h, l); Th[q * 4 + 2][r] = h; Tl[q * 4 + 2][r] = l;
    split_bf(v.w, h, l); Th[q * 4 + 3][r] = h; Tl[q * 4 + 3][r] = l;
    __syncthreads();
    short4v oh, ol;
    oh.x = Th[r][q * 4 + 0]; ol.x = Tl[r][q * 4 + 0];
    oh.y = Th[r][q * 4 + 1]; ol.y = Tl[r][q * 4 + 1];
    oh.z = Th[r][q * 4 + 2]; ol.z = Tl[r][q * 4 + 2];
    oh.w = Th[r][q * 4 + 3]; ol.w = Tl[r][q * 4 + 3];
    size_t o = (size_t)b * CC * NPIX + (size_t)(n0 + r) * 256 + c0 + q * 4;
    *(short4v*)(ohi + o) = oh;
    *(short4v*)(olo + o) = ol;
}

// Vt[c][m] = x3b.flat[m*256+c] (already bf16). grid (128,8,4)
__global__ __launch_bounds__(256) void packVt_bf(
    const short* __restrict__ x3b, short* __restrict__ Vt)
{
    __shared__ short T[32][33];
    const int b  = blockIdx.z;
    const int m0 = blockIdx.x * 32;
    const int c0 = blockIdx.y * 32;
    const short* in = x3b + (size_t)b * CC * NPIX;
    short* out = Vt + (size_t)b * CC * NPIX;
    const int t = threadIdx.x;
    const int r = t >> 3, q = t & 7;
    short4v v = *(const short4v*)(in + (size_t)(m0 + r) * CC + c0 + q * 4);
    T[q * 4 + 0][r] = v.x;
    T[q * 4 + 1][r] = v.y;
    T[q * 4 + 2][r] = v.z;
    T[q * 4 + 3][r] = v.w;
    __syncthreads();
    short4v o;
    o.x = T[r][q * 4 + 0];
    o.y = T[r][q * 4 + 1];
    o.z = T[r][q * 4 + 2];
    o.w = T[r][q * 4 + 3];
    *(short4v*)(out + (size_t)(c0 + r) * NPIX + m0 + q * 4) = o;
}

// ---------------- GEMM kernels ----------------

// proj. grid (32, 2, 12). p=0 -> x1 hi/lo, p=1 -> x2 fp32, p=2 -> x3 bf16.
__global__ __launch_bounds__(256) void proj_mfma(
    const short* __restrict__ wphi, const short* __restrict__ wplo,
    const short* __restrict__ xthi, const short* __restrict__ xtlo,
    const float* __restrict__ b_teta, const float* __restrict__ b_fi,
    const float* __restrict__ b_gi,
    short* __restrict__ x1hi, short* __restrict__ x1lo,
    float* __restrict__ x2, short* __restrict__ x3b)
{
    const int z = blockIdx.z, p = z >> 2, b = z & 3;
    const int n0 = blockIdx.x * 128, c0 = blockIdx.y * 128;
    const size_t CN = (size_t)CC * NPIX;
    const short* Ah = wphi + p * 65536 + c0 * 256;
    const short* Al = wplo + p * 65536 + c0 * 256;
    const short* Bh = xthi + (size_t)b * CN + (size_t)n0 * 256;
    const short* Bl = xtlo + (size_t)b * CN + (size_t)n0 * 256;
    const float* bias = p == 0 ? b_teta : p == 1 ? b_fi : b_gi;

    f32x16 acc[2][2] = {};
    mfma_core_hilo(Ah, Al, Bh, Bl, acc);

    const int t = threadIdx.x, lane = t & 63, w = t >> 6;
    const int l31 = lane & 31, l5 = lane >> 5;
    const int aq = (w & 1) * 64, bq = (w >> 1) * 64;
#pragma unroll
    for (int s = 0; s < 2; s++)
#pragma unroll
        for (int u = 0; u < 2; u++)
#pragma unroll
            for (int r = 0; r < 16; r++) {
                int c = c0 + aq + s * 32 + cdrow(r, l5);
                int n = n0 + bq + u * 32 + l31;
                float v = acc[s][u][r] + bias[c];
                size_t o = (size_t)b * CN + (size_t)c * NPIX + n;
                if (p == 0) {
                    short h, l; split_bf(v, h, l);
                    x1hi[o] = h; x1lo[o] = l;
                } else if (p == 1) {
                    x2[o] = v;
                } else {
                    x3b[o] = f2bf(v);
                }
            }
}

// scores + fused column partial stats. grid (32, 32) per batch.
// Writes S fp32 and per-64-row-half column partials (64 partials/column).
// NOTE: a lane's 16 acc values cover only 16 of 32 tile rows (l5 split) —
// partner rows live in lane^32; combine via shuffle before writing.
__global__ __launch_bounds__(256) void scores_mfma(
    const short* __restrict__ x1hi, const short* __restrict__ x1lo,
    const short* __restrict__ x2thi, const short* __restrict__ x2tlo,
    float* __restrict__ S, float* __restrict__ pm, float* __restrict__ pl)
{
    const int m0 = blockIdx.x * 128, n0 = blockIdx.y * 128;
    f32x16 acc[2][2] = {};
    mfma_core_hilo(x1hi + (size_t)n0 * 256, x1lo + (size_t)n0 * 256,
                   x2thi + (size_t)m0 * 256, x2tlo + (size_t)m0 * 256, acc);

    const int t = threadIdx.x, lane = t & 63, w = t >> 6;
    const int l31 = lane & 31, l5 = lane >> 5;
    const int aq = (w & 1) * 64, bq = (w >> 1) * 64;
#pragma unroll
    for (int s = 0; s < 2; s++)
#pragma unroll
        for (int u = 0; u < 2; u++)
#pragma unroll
            for (int r = 0; r < 16; r++) {
                int n = n0 + aq + s * 32 + cdrow(r, l5);
                int m = m0 + bq + u * 32 + l31;
                S[(size_t)n * NPIX + m] = acc[s][u][r];
            }

    // column partial stats over this block's 64-row half (member = w&1).
    const int member = w & 1;
#pragma unroll
    for (int u = 0; u < 2; u++) {
        float vmax = -1e30f;
#pragma unroll
        for (int s = 0; s < 2; s++)
#pragma unroll
            for (int r = 0; r < 16; r++) vmax = fmaxf(vmax, acc[s][u][r]);
        float vsum = 0.0f;
#pragma unroll
        for (int s = 0; s < 2; s++)
#pragma unroll
            for (int r = 0; r < 16; r++) vsum += __expf(acc[s][u][r] - vmax);
        // combine with partner lane (lane^32) holding the other 16 rows/stripe
        float vmax2 = __shfl_xor(vmax, 32, 64);
        float vsum2 = __shfl_xor(vsum, 32, 64);
        float mc = fmaxf(vmax, vmax2);
        float sc = vsum * __expf(vmax - mc) + vsum2 * __expf(vmax2 - mc);
        if (l5 == 0) {
            size_t pidx = (size_t)(blockIdx.y * 2 + member) * NPIX + m0 + bq + u * 32 + l31;
            pm[pidx] = mc;
            pl[pidx] = sc;
        }
    }
}

// out: relu(x + bias + W.Y^T), single batch. grid (32, 4)
__global__ __launch_bounds__(256) void out_mfma(
    const short* __restrict__ wob,
    const float* __restrict__ b_o1, const float* __restrict__ b_o2,
    const short* __restrict__ Y1s, const short* __restrict__ Y2s,
    const float* __restrict__ x, float* __restrict__ out, int b)
{
    const int ch0 = blockIdx.y * 128;
    const int pix0 = blockIdx.x * 128;
    const short* W = wob + (ch0 < 256 ? 0 : 65536) + (size_t)(ch0 & 255) * 256;
    const short* Y = (ch0 < 256 ? Y1s : Y2s) + (size_t)pix0 * 256;
    const float* bias = ch0 < 256 ? b_o1 : b_o2;

    f32x16 acc[2][2] = {};
    mfma_core_single(W, Y, acc);

    const int t = threadIdx.x, lane = t & 63, w = t >> 6;
    const int l31 = lane & 31, l5 = lane >> 5;
    const int aq = (w & 1) * 64, bq = (w >> 1) * 64;
#pragma unroll
    for (int s = 0; s < 2; s++)
#pragma unroll
        for (int u = 0; u < 2; u++)
#pragma unroll
            for (int r = 0; r < 16; r++) {
                int ch = ch0 + aq + s * 32 + cdrow(r, l5);
                int pix = pix0 + bq + u * 32 + l31;
                int chm = ch & 255;
                float v = acc[s][u][r] + bias[chm] +
                          x[((size_t)b * CC + chm) * NPIX + pix];
                out[((size_t)b * 2 * CC + ch) * NPIX + pix] = fmaxf(v, 0.0f);
            }
}

// combine 64 col partials. grid (16)
__global__ __launch_bounds__(256) void colstats2_kernel(
    const float* __restrict__ pm, const float* __restrict__ pl,
    float* __restrict__ cm, float* __restrict__ cli)
{
    int col = blockIdx.x * 256 + threadIdx.x;
    float m = -1e30f, l = 0.0f;
    for (int i = 0; i < 64; i++) {
        float m2 = pm[(size_t)i * NPIX + col];
        float l2 = pl[(size_t)i * NPIX + col];
        float mn = fmaxf(m, m2);
        l = l * __expf(m - mn) + l2 * __expf(m2 - mn);
        m = mn;
    }
    cm[col]  = m;
    cli[col] = 1.0f / l;
}

// ---------------- fused row-stats + P materialization ----------------
__global__ __launch_bounds__(256) void rowexpP_kernel(
    const float* __restrict__ S, int n_off,
    const float* __restrict__ colm, const float* __restrict__ colli,
    short* __restrict__ P1, short* __restrict__ P2)
{
    const int row = blockIdx.x;
    const int n = n_off + row;
    const float* sp = S + (size_t)n * NPIX;
    const int t = threadIdx.x;
    const int w = t >> 6, lane = t & 63;
    __shared__ float red[4];

    float4 s4[4];
#pragma unroll
    for (int i = 0; i < 4; i++)
        s4[i] = *(const float4*)(sp + (i * 256 + t) * 4);

    float m = -1e30f;
#pragma unroll
    for (int i = 0; i < 4; i++) {
        m = fmaxf(m, fmaxf(fmaxf(s4[i].x, s4[i].y), fmaxf(s4[i].z, s4[i].w)));
    }
    for (int off = 32; off; off >>= 1) m = fmaxf(m, __shfl_xor(m, off, 64));
    if (lane == 0) red[w] = m;
    __syncthreads();
    m = fmaxf(fmaxf(red[0], red[1]), fmaxf(red[2], red[3]));
    __syncthreads();

    float e[16];
    float sum = 0.0f;
#pragma unroll
    for (int i = 0; i < 4; i++) {
        e[i * 4 + 0] = __expf(s4[i].x - m);
        e[i * 4 + 1] = __expf(s4[i].y - m);
        e[i * 4 + 2] = __expf(s4[i].z - m);
        e[i * 4 + 3] = __expf(s4[i].w - m);
        sum += e[i * 4 + 0] + e[i * 4 + 1] + e[i * 4 + 2] + e[i * 4 + 3];
    }
    for (int off = 32; off; off >>= 1) sum += __shfl_xor(sum, off, 64);
    if (lane == 0) red[w] = sum;
    __syncthreads();
    float rl = 1.0f / (red[0] + red[1] + red[2] + red[3]);

    short* p1 = P1 + (size_t)row * NPIX;
    short* p2 = P2 + (size_t)row * NPIX;
#pragma unroll
    for (int i = 0; i < 4; i++) {
        int idx = (i * 256 + t) * 4;
        float4 cm4 = *(const float4*)(colm + idx);
        float4 cl4 = *(const float4*)(colli + idx);
        short4v a, bvv;
        a.x = f2bf(e[i * 4 + 0] * rl);
        a.y = f2bf(e[i * 4 + 1] * rl);
        a.z = f2bf(e[i * 4 + 2] * rl);
        a.w = f2bf(e[i * 4 + 3] * rl);
        bvv.x = f2bf(__expf(s4[i].x - cm4.x) * cl4.x);
        bvv.y = f2bf(__expf(s4[i].y - cm4.y) * cl4.y);
        bvv.z = f2bf(__expf(s4[i].z - cm4.z) * cl4.z);
        bvv.w = f2bf(__expf(s4[i].w - cm4.w) * cl4.w);
        *(short4v*)(p1 + idx) = a;
        *(short4v*)(p2 + idx) = bvv;
    }
}

// ---------------- Y = P @ Vt^T (deep-K bf16 GEMM, K-step 128, pipelined) ----
__global__ __launch_bounds__(256) void ygemm_kernel(
    const short* __restrict__ P1a, const short* __restrict__ P1b,
    const short* __restrict__ P2a, const short* __restrict__ P2b,
    const short* __restrict__ Vt,
    short* __restrict__ Y1s, short* __restrict__ Y2s)
{
    __shared__ short LA[64 * YST2], LB[64 * YST2];
    const int mode = blockIdx.z;
    const int n0 = blockIdx.y * 64;
    const int c0 = blockIdx.x * 64;
    const short* Pa_ = mode ? P2a : P1a;
    const short* Pb_ = mode ? P2b : P1b;
    const short* A = (n0 < 2048) ? (Pa_ + (size_t)n0 * NPIX)
                                 : (Pb_ + (size_t)(n0 - 2048) * NPIX);
    const short* B = Vt + (size_t)c0 * NPIX;

    const int t = threadIdx.x, lane = t & 63, w = t >> 6;
    const int l31 = lane & 31, l5 = lane >> 5;
    const int nst = (w & 1) * 32, cst = (w >> 1) * 32;
    const int tr = t >> 2;            // staging row 0..63
    const int tk = (t & 3) * 32;      // staging k offset (shorts)

    bf16x8 ra[4], rb[4];
#pragma unroll
    for (int j = 0; j < 4; j++) {
        ra[j] = *(const bf16x8*)(A + (size_t)tr * NPIX + tk + j * 8);
        rb[j] = *(const bf16x8*)(B + (size_t)tr * NPIX + tk + j * 8);
    }

    f32x16 acc = {};
    for (int k0 = 0; k0 < NPIX; k0 += 128) {
        __syncthreads();
#pragma unroll
        for (int j = 0; j < 4; j++) {
            *(bf16x8*)&LA[tr * YST2 + tk + j * 8] = ra[j];
            *(bf16x8*)&LB[tr * YST2 + tk + j * 8] = rb[j];
        }
        __syncthreads();
        if (k0 + 128 < NPIX) {
            size_t g = (size_t)k0 + 128 + tk;
#pragma unroll
            for (int j = 0; j < 4; j++) {
                ra[j] = *(const bf16x8*)(A + (size_t)tr * NPIX + g + j * 8);
                rb[j] = *(const bf16x8*)(B + (size_t)tr * NPIX + g + j * 8);
            }
        }
#pragma unroll
        for (int kc = 0; kc < 8; kc++) {
            bf16x8 af = *(const bf16x8*)&LA[(nst + l31) * YST2 + kc * 16 + l5 * 8];
            bf16x8 bf = *(const bf16x8*)&LB[(cst + l31) * YST2 + kc * 16 + l5 * 8];
            acc = __builtin_amdgcn_mfma_f32_32x32x16_bf16(af, bf, acc, 0, 0, 0);
        }
    }
    short* Y = mode ? Y2s : Y1s;
#pragma unroll
    for (int r = 0; r < 16; r++) {
        int rr = cdrow(r, l5);
        Y[(size_t)(n0 + nst + rr) * CC + c0 + cst + l31] = f2bf(acc[r]);
    }
}

extern "C" void kernel_launch(void* const* d_in, const int* in_sizes, int n_in,
                              void* d_out, int out_size, void* d_ws, size_t ws_size,
                              hipStream_t stream)
{
    (void)in_sizes; (void)n_in; (void)out_size; (void)ws_size;
    const float* x      = (const float*)d_in[0];
    const float* w_teta = (const float*)d_in[1];
    const float* b_teta = (const float*)d_in[2];
    const float* w_fi   = (const float*)d_in[3];
    const float* b_fi   = (const float*)d_in[4];
    const float* w_gi   = (const float*)d_in[5];
    const float* b_gi   = (const float*)d_in[6];
    const float* w_o1   = (const float*)d_in[7];
    const float* b_o1   = (const float*)d_in[8];
    const float* w_o2   = (const float*)d_in[9];
    const float* b_o2   = (const float*)d_in[10];
    float* out = (float*)d_out;

    const size_t CN = (size_t)CC * NPIX;       // 1M elements
    const size_t HALF = (size_t)2048 * NPIX;   // 8M shorts = 16 MB
    float* ws    = (float*)d_ws;
    // --- persistent regions ---
    float* S     = ws;                          // 64 MB
    short* Pfr   = (short*)(S + (size_t)NPIX * NPIX);  // 32 MB (P1a+P2a)
    short* x1hi  = Pfr + 2 * HALF;              // 8 MB each
    short* x1lo  = x1hi + BB * CN;
    short* x2thi = x1lo + BB * CN;
    short* x2tlo = x2thi + BB * CN;
    short* Vtb   = x2tlo + BB * CN;             // 8 MB
    short* Y1s   = Vtb + BB * CN;               // 2 MB
    short* Y2s   = Y1s + CN;                    // 2 MB
    float* cm    = (float*)(Y2s + CN);
    float* cli   = cm + NPIX;
    float* pm    = cli + NPIX;                  // 64*NPIX = 1 MB
    float* pl    = pm + 64 * NPIX;              // 1 MB
    short* wphi  = (short*)(pl + 64 * NPIX);    // 3*65536
    short* wplo  = wphi + 3 * 65536;
    short* wob   = wplo + 3 * 65536;            // 2*65536
    // --- aliases ---
    short* xthi = (short*)S;                    // pre-phase only (16 MB in S)
    short* xtlo = xthi + BB * CN;
    float* x2   = (float*)Pfr;                  // pre-phase only (16 MB)
    short* x3b  = (short*)(x2 + BB * CN);       // pre-phase only (8 MB)
    // P halves: a-halves in Pfr, b-halves overwrite S's first 32 MB
    short* P1a = Pfr;
    short* P2a = Pfr + HALF;
    short* P1b = (short*)S;
    short* P2b = (short*)S + HALF;

    dim3 blk(256);
    pack_w_hilo<<<dim3(64, 3), blk, 0, stream>>>(w_teta, w_fi, w_gi, wphi, wplo);
    pack_w_out<<<dim3(64, 2), blk, 0, stream>>>(w_o1, w_o2, wob);
    pack_t_split<<<dim3(128, 8, 4), blk, 0, stream>>>(x, xthi, xtlo);

    proj_mfma<<<dim3(32, 2, 12), blk, 0, stream>>>(
        wphi, wplo, xthi, xtlo, b_teta, b_fi, b_gi, x1hi, x1lo, x2, x3b);

    pack_t_split<<<dim3(128, 8, 4), blk, 0, stream>>>(x2, x2thi, x2tlo);
    packVt_bf<<<dim3(128, 8, 4), blk, 0, stream>>>(x3b, Vtb);

    for (int b = 0; b < BB; b++) {
        scores_mfma<<<dim3(32, 32), blk, 0, stream>>>(
            x1hi + b * CN, x1lo + b * CN, x2thi + b * CN, x2tlo + b * CN, S, pm, pl);
        colstats2_kernel<<<dim3(16), blk, 0, stream>>>(pm, pl, cm, cli);
        // half 1: rows [0,2048) -> Pfr ; half 2: rows [2048,4096) -> S base
        rowexpP_kernel<<<dim3(2048), blk, 0, stream>>>(S, 0, cm, cli, P1a, P2a);
        rowexpP_kernel<<<dim3(2048), blk, 0, stream>>>(S, 2048, cm, cli, P1b, P2b);
        ygemm_kernel<<<dim3(4, 64, 2), blk, 0, stream>>>(
            P1a, P1b, P2a, P2b, Vtb + b * CN, Y1s, Y2s);
        out_mfma<<<dim3(32, 4), blk, 0, stream>>>(
            wob, b_o1, b_o2, Y1s, Y2s, x, out, b);
    }
}